// Round 11
// baseline (226.890 us; speedup 1.0000x reference)
//
#include <hip/hip_runtime.h>
#include <math.h>

#define Bc     16
#define HIDc   2048
#define Hc     32
#define Dc     64
#define KVc    4096
#define QKVO   6144        // 3*H*D
#define SCALEc 0.125f      // D^-0.5
#define CHUNKS 4
#define CHUNK  1024        // KVc / CHUNKS

typedef float f4v __attribute__((ext_vector_type(4)));   // native vector for nontemporal builtins

// ---------------- Kernel 1: qkv = x @ w_qkv^T, batch-amortized (UNCHANGED from R10) ----------------
__global__ __launch_bounds__(256) void qkv_kernel2(const float* __restrict__ x,
                                                   const float* __restrict__ w,
                                                   float* __restrict__ qkv) {
    __shared__ float4 xs[8 * 512];   // 64 KB: 8 batches x 2048 floats
    int blk = blockIdx.x;            // 2 bgroups * 384 rowblocks = 768
    int bg  = blk & 1;
    int rb  = blk >> 1;              // 0..383
    int t = threadIdx.x, lane = t & 63, wid = t >> 6;
    const float4* xbase = reinterpret_cast<const float4*>(x) + (size_t)bg * 8 * 512;
#pragma unroll
    for (int i = 0; i < 16; ++i) xs[t + 256 * i] = xbase[t + 256 * i];
    __syncthreads();
#pragma unroll 2
    for (int rr = 0; rr < 4; ++rr) {
        int o = rb * 16 + wid * 4 + rr;
        const float4* wr = reinterpret_cast<const float4*>(w + (size_t)o * HIDc);
        float acc[8] = {0.f, 0.f, 0.f, 0.f, 0.f, 0.f, 0.f, 0.f};
#pragma unroll
        for (int j = 0; j < 8; ++j) {
            float4 wv = wr[lane + 64 * j];
#pragma unroll
            for (int bi = 0; bi < 8; ++bi) {
                float4 xv = xs[bi * 512 + lane + 64 * j];
                acc[bi] += wv.x * xv.x + wv.y * xv.y + wv.z * xv.z + wv.w * xv.w;
            }
        }
#pragma unroll
        for (int bi = 0; bi < 8; ++bi) {
#pragma unroll
            for (int off = 32; off >= 1; off >>= 1) acc[bi] += __shfl_xor(acc[bi], off);
        }
        if (lane == 0) {
#pragma unroll
            for (int bi = 0; bi < 8; ++bi)
                qkv[(size_t)(bg * 8 + bi) * QKVO + o] = acc[bi];
        }
    }
}

// ---------------- Kernel 2a: one-pass chunked attention, 3-deep prefetch ----------------
// Prefetch distance 2 (~two compute phases ~800cy) covers HBM latency (~900cy) at
// every COMPUTE entry. Buffers A/B/C rotate; ~120 VGPR under the (256,4) cap.
__global__ __launch_bounds__(256, 4) void attn_chunk_kernel(const float* __restrict__ qkv,
                                                            const float* __restrict__ bias,
                                                            const float* __restrict__ past_kv,
                                                            float* __restrict__ part_o,
                                                            float* __restrict__ part_s) {
    __shared__ float bs[CHUNK];       // bias slice, 4 KB
    __shared__ float accs[16][65];    // subgroup partial O (padded)
    __shared__ float ps[16];

    int blk = blockIdx.x;
    int c   = blk & (CHUNKS - 1);
    int bh  = blk >> 2;               // b*32 + h
    int h   = bh & 31;
    int b   = bh >> 5;
    int t    = threadIdx.x;
    int lane = t & 63;
    int wid  = t >> 6;
    int sg   = lane >> 4;
    int cg   = lane & 15;
    int row0 = c * CHUNK;

    reinterpret_cast<float4*>(bs)[t] =
        reinterpret_cast<const float4*>(bias + (size_t)bh * KVc + row0)[t];

    const float* qp = qkv + (size_t)b * QKVO + h * Dc;
    float4 q4 = reinterpret_cast<const float4*>(qp)[cg];

    const size_t kvstride = (size_t)KVc * Dc;
    const float* pastK = past_kv + (size_t)bh * kvstride + (size_t)row0 * Dc;
    const float* pastV = past_kv + (size_t)(Bc * Hc) * kvstride + (size_t)bh * kvstride
                         + (size_t)row0 * Dc;

    __syncthreads();

    int rbase = wid * 4 + sg;         // 16 subgroups cover 16 consecutive rows
    float s = 0.f;
    float4 acc = {0.f, 0.f, 0.f, 0.f};

    f4v kA[4], vA[4], kB[4], vB[4], kC[4], vC[4];

    auto LOAD = [&](int ot, f4v (&k4)[4], f4v (&v4)[4]) {
        int it = ot * 4;
#pragma unroll
        for (int u = 0; u < 4; ++u) {
            int rl = (it + u) * 16 + rbase;
            k4[u] = __builtin_nontemporal_load(
                        reinterpret_cast<const f4v*>(pastK + (size_t)rl * Dc) + cg);
        }
#pragma unroll
        for (int u = 0; u < 4; ++u) {
            int rl = (it + u) * 16 + rbase;
            v4[u] = __builtin_nontemporal_load(
                        reinterpret_cast<const f4v*>(pastV + (size_t)rl * Dc) + cg);
        }
    };
    auto COMPUTE = [&](int ot, f4v (&k4)[4], f4v (&v4)[4]) {
        int it = ot * 4;
        float es = 0.f;
        float4 va = {0.f, 0.f, 0.f, 0.f};
#pragma unroll
        for (int u = 0; u < 4; ++u) {
            int rl = (it + u) * 16 + rbase;
            float pp = q4.x * k4[u].x + q4.y * k4[u].y + q4.z * k4[u].z + q4.w * k4[u].w;
            pp += __shfl_xor(pp, 1);
            pp += __shfl_xor(pp, 2);
            pp += __shfl_xor(pp, 4);
            pp += __shfl_xor(pp, 8);
            float e = __expf(fmaf(pp, SCALEc, bs[rl]));
            es += e;
            va.x = fmaf(e, v4[u].x, va.x);
            va.y = fmaf(e, v4[u].y, va.y);
            va.z = fmaf(e, v4[u].z, va.z);
            va.w = fmaf(e, v4[u].w, va.w);
        }
        s += es;
        acc.x += va.x;
        acc.y += va.y;
        acc.z += va.z;
        acc.w += va.w;
    };

    int nclean = (c == CHUNKS - 1) ? 15 : 16;   // peel last 64 rows of last chunk
    LOAD(0, kA, vA);
    LOAD(1, kB, vB);
    int ot = 0;
    while (true) {
        if (ot + 2 < nclean) LOAD(ot + 2, kC, vC);
        COMPUTE(ot, kA, vA);
        if (++ot >= nclean) break;
        if (ot + 2 < nclean) LOAD(ot + 2, kA, vA);
        COMPUTE(ot, kB, vB);
        if (++ot >= nclean) break;
        if (ot + 2 < nclean) LOAD(ot + 2, kB, vB);
        COMPUTE(ot, kC, vC);
        if (++ot >= nclean) break;
    }

    if (c == CHUNKS - 1) {
        const float* knew = qkv + (size_t)b * QKVO + HIDc + h * Dc;
        const float* vnew = qkv + (size_t)b * QKVO + 2 * HIDc + h * Dc;
        int it = 60;
        float4 k4[4], v4[4];
#pragma unroll
        for (int u = 0; u < 4; ++u) {
            int rl = (it + u) * 16 + rbase;
            const float* kr = (rl == CHUNK - 1) ? knew : (pastK + (size_t)rl * Dc);
            k4[u] = reinterpret_cast<const float4*>(kr)[cg];
        }
#pragma unroll
        for (int u = 0; u < 4; ++u) {
            int rl = (it + u) * 16 + rbase;
            const float* vr = (rl == CHUNK - 1) ? vnew : (pastV + (size_t)rl * Dc);
            v4[u] = reinterpret_cast<const float4*>(vr)[cg];
        }
#pragma unroll
        for (int u = 0; u < 4; ++u) {
            int rl = (it + u) * 16 + rbase;
            float pp = q4.x * k4[u].x + q4.y * k4[u].y + q4.z * k4[u].z + q4.w * k4[u].w;
            pp += __shfl_xor(pp, 1);
            pp += __shfl_xor(pp, 2);
            pp += __shfl_xor(pp, 4);
            pp += __shfl_xor(pp, 8);
            float e = __expf(fmaf(pp, SCALEc, bs[rl]));
            s += e;
            acc.x = fmaf(e, v4[u].x, acc.x);
            acc.y = fmaf(e, v4[u].y, acc.y);
            acc.z = fmaf(e, v4[u].z, acc.z);
            acc.w = fmaf(e, v4[u].w, acc.w);
        }
    }

    int sgid = wid * 4 + sg;
    if (cg == 0) ps[sgid] = s;
    accs[sgid][cg * 4 + 0] = acc.x;
    accs[sgid][cg * 4 + 1] = acc.y;
    accs[sgid][cg * 4 + 2] = acc.z;
    accs[sgid][cg * 4 + 3] = acc.w;
    __syncthreads();
    if (t < 64) {
        float S = 0.f, o = 0.f;
#pragma unroll
        for (int i = 0; i < 16; ++i) {
            S += ps[i];
            o += accs[i][t];
        }
        part_o[((size_t)bh * CHUNKS + c) * Dc + t] = o;
        if (t == 0) part_s[(size_t)bh * CHUNKS + c] = S;
    }
}

// ---------------- Kernel 3: out = attn @ w_o^T, batch-amortized + fused combine (UNCHANGED) ----------------
__global__ __launch_bounds__(256) void outproj_kernel2(const float* __restrict__ part_o,
                                                       const float* __restrict__ part_s,
                                                       const float* __restrict__ w_o,
                                                       float* __restrict__ out) {
    __shared__ float4 as[8 * 512];   // 64 KB: 8 batches x 2048 floats (normalized attn)
    int blk = blockIdx.x;            // 2 bgroups * 128 rowblocks = 256
    int bg  = blk & 1;
    int rb  = blk >> 1;              // 0..127
    int t = threadIdx.x, lane = t & 63, wid = t >> 6;

#pragma unroll
    for (int i = 0; i < 16; ++i) {
        int idx = t + 256 * i;            // bi*512 + c4
        int bi  = idx >> 9;
        int c4  = idx & 511;
        int h   = c4 >> 4;
        int q4i = c4 & 15;
        int bh  = (bg * 8 + bi) * Hc + h;
        const float4* po = reinterpret_cast<const float4*>(part_o) + (size_t)bh * 64 + q4i;
        float4 v0 = po[0], v1 = po[16], v2 = po[32], v3 = po[48];
        float S = part_s[bh * 4 + 0] + part_s[bh * 4 + 1]
                + part_s[bh * 4 + 2] + part_s[bh * 4 + 3];
        float si = 1.0f / S;
        float4 r;
        r.x = (v0.x + v1.x + v2.x + v3.x) * si;
        r.y = (v0.y + v1.y + v2.y + v3.y) * si;
        r.z = (v0.z + v1.z + v2.z + v3.z) * si;
        r.w = (v0.w + v1.w + v2.w + v3.w) * si;
        as[idx] = r;
    }
    __syncthreads();
#pragma unroll 2
    for (int rr = 0; rr < 4; ++rr) {
        int f = rb * 16 + wid * 4 + rr;
        const float4* wr = reinterpret_cast<const float4*>(w_o + (size_t)f * HIDc);
        float acc[8] = {0.f, 0.f, 0.f, 0.f, 0.f, 0.f, 0.f, 0.f};
#pragma unroll
        for (int j = 0; j < 8; ++j) {
            float4 wv = wr[lane + 64 * j];
#pragma unroll
            for (int bi = 0; bi < 8; ++bi) {
                float4 av = as[bi * 512 + lane + 64 * j];
                acc[bi] += wv.x * av.x + wv.y * av.y + wv.z * av.z + wv.w * av.w;
            }
        }
#pragma unroll
        for (int bi = 0; bi < 8; ++bi) {
#pragma unroll
            for (int off = 32; off >= 1; off >>= 1) acc[bi] += __shfl_xor(acc[bi], off);
        }
        if (lane == 0) {
#pragma unroll
            for (int bi = 0; bi < 8; ++bi)
                out[(size_t)(bg * 8 + bi) * HIDc + f] = acc[bi];
        }
    }
}

extern "C" void kernel_launch(void* const* d_in, const int* in_sizes, int n_in,
                              void* d_out, int out_size, void* d_ws, size_t ws_size,
                              hipStream_t stream) {
    const float* x       = (const float*)d_in[0];
    const float* bias    = (const float*)d_in[1];
    const float* past_kv = (const float*)d_in[2];
    const float* w_qkv   = (const float*)d_in[3];
    const float* w_o     = (const float*)d_in[4];
    float* out = (float*)d_out;

    float* qkv    = (float*)d_ws;                           // 16*6144
    float* part_o = qkv + (size_t)Bc * QKVO;                // 16*32*4*64
    float* part_s = part_o + (size_t)Bc * Hc * CHUNKS * Dc; // 16*32*4

    qkv_kernel2<<<dim3(768), dim3(256), 0, stream>>>(x, w_qkv, qkv);
    attn_chunk_kernel<<<dim3(Bc * Hc * CHUNKS), dim3(256), 0, stream>>>(qkv, bias, past_kv, part_o, part_s);
    outproj_kernel2<<<dim3(256), dim3(256), 0, stream>>>(part_o, part_s, w_o, out);
}